// Round 1
// baseline (3925.313 us; speedup 1.0000x reference)
//
#include <hip/hip_runtime.h>

#define B_ROWS 262144
#define K_CODES 1024
#define DIM 64

// output layout (floats)
#define OUT_ZQ 0
#define OUT_IDX 16777216
#define OUT_LOSS 17039360
#define OUT_NEWCS 17039361
#define OUT_NEWES 17040385
#define OUT_NEWW 17105921

// ws layout (floats)
#define WS_LOSS 0
#define WS_COUNTS 16
#define WS_W2 2048
#define WS_SMOOTH 3072
#define WS_EMBED 4096
#define WS_ZERO_FLOATS (4096 + 65536)

__global__ __launch_bounds__(256) void vq_w2_kernel(const float* __restrict__ w,
                                                    float* __restrict__ w2) {
    int k = blockIdx.x * 256 + threadIdx.x;
    if (k < K_CODES) {
        const float4* w4 = (const float4*)(w + (size_t)k * DIM);
        float s = 0.f;
#pragma unroll
        for (int j = 0; j < 16; ++j) {
            float4 v = w4[j];
            s += v.x * v.x + v.y * v.y + v.z * v.z + v.w * v.w;
        }
        w2[k] = s;
    }
}

__global__ __launch_bounds__(256) void vq_main_kernel(
    const float* __restrict__ z, const float* __restrict__ w,
    float* __restrict__ ws, float* __restrict__ out) {
    __shared__ float hist[K_CODES];
    __shared__ float lred[4];
    const float* __restrict__ w2 = ws + WS_W2;

    int tid = threadIdx.x;
    for (int i = tid; i < K_CODES; i += 256) hist[i] = 0.f;
    __syncthreads();

    int row = blockIdx.x * 256 + tid;

    // load z row into registers (16 x float4)
    const float4* zp = (const float4*)(z + (size_t)row * DIM);
    float zr[DIM];
    float z2 = 0.f;
#pragma unroll
    for (int j = 0; j < 16; ++j) {
        float4 v = zp[j];
        zr[4 * j + 0] = v.x;
        zr[4 * j + 1] = v.y;
        zr[4 * j + 2] = v.z;
        zr[4 * j + 3] = v.w;
    }
#pragma unroll
    for (int d = 0; d < DIM; ++d) z2 = fmaf(zr[d], zr[d], z2);

    // argmin over all codes; d2 = (z2 - 2*dot) + w2[k]; first-min tie-break
    float minv = 3.4e38f;
    int mini = 0;
    for (int k = 0; k < K_CODES; k += 2) {
        const float4* wa = (const float4*)(w + (size_t)k * DIM);
        const float4* wb = (const float4*)(w + (size_t)(k + 1) * DIM);
        float a0 = 0.f, a1 = 0.f;
#pragma unroll
        for (int j = 0; j < 16; ++j) {
            float4 va = wa[j];
            float4 vb = wb[j];
            a0 = fmaf(zr[4 * j + 0], va.x, a0);
            a0 = fmaf(zr[4 * j + 1], va.y, a0);
            a0 = fmaf(zr[4 * j + 2], va.z, a0);
            a0 = fmaf(zr[4 * j + 3], va.w, a0);
            a1 = fmaf(zr[4 * j + 0], vb.x, a1);
            a1 = fmaf(zr[4 * j + 1], vb.y, a1);
            a1 = fmaf(zr[4 * j + 2], vb.z, a1);
            a1 = fmaf(zr[4 * j + 3], vb.w, a1);
        }
        float d0 = (z2 - 2.f * a0) + w2[k];
        float d1 = (z2 - 2.f * a1) + w2[k + 1];
        if (d0 < minv) { minv = d0; mini = k; }
        if (d1 < minv) { minv = d1; mini = k + 1; }
    }

    // gather z_q (old weights), write z_q_st = z + (z_q - z), accumulate loss
    const float4* wq4 = (const float4*)(w + (size_t)mini * DIM);
    float4* outp = (float4*)(out + OUT_ZQ + (size_t)row * DIM);
    float lsum = 0.f;
#pragma unroll
    for (int j = 0; j < 16; ++j) {
        float4 q = wq4[j];
        float x0 = zr[4 * j + 0], x1 = zr[4 * j + 1];
        float x2 = zr[4 * j + 2], x3 = zr[4 * j + 3];
        float4 st;
        st.x = x0 + (q.x - x0);
        st.y = x1 + (q.y - x1);
        st.z = x2 + (q.z - x2);
        st.w = x3 + (q.w - x3);
        outp[j] = st;
        float e0 = x0 - q.x, e1 = x1 - q.y, e2 = x2 - q.z, e3 = x3 - q.w;
        lsum += e0 * e0;
        lsum += e1 * e1;
        lsum += e2 * e2;
        lsum += e3 * e3;
    }
    out[OUT_IDX + row] = (float)mini;

    // embed segment-sum: 64 global fp32 atomics per row into ws accumulator
    float* emb = ws + WS_EMBED + (size_t)mini * DIM;
#pragma unroll
    for (int d = 0; d < DIM; ++d) atomicAdd(&emb[d], zr[d]);

    // cluster counts: LDS histogram, then one global atomic per nonzero bin
    atomicAdd(&hist[mini], 1.f);

    // loss: wave reduce + block reduce + one global atomic per block
#pragma unroll
    for (int o = 32; o; o >>= 1) lsum += __shfl_down(lsum, o, 64);
    if ((tid & 63) == 0) lred[tid >> 6] = lsum;
    __syncthreads();
    if (tid == 0) atomicAdd(ws + WS_LOSS, lred[0] + lred[1] + lred[2] + lred[3]);

    for (int i = tid; i < K_CODES; i += 256) {
        float c = hist[i];
        if (c != 0.f) atomicAdd(ws + WS_COUNTS + i, c);
    }
}

__global__ __launch_bounds__(1024) void vq_finalize1_kernel(
    const float* __restrict__ ema_cs, float* __restrict__ ws,
    float* __restrict__ out) {
    int k = threadIdx.x;  // 1024 threads, one per code
    float nc = 0.99f * ema_cs[k] + 0.01f * (ws + WS_COUNTS)[k];
    out[OUT_NEWCS + k] = nc;

    // block-wide sum n = sum(new_cs)
    float s = nc;
#pragma unroll
    for (int o = 32; o; o >>= 1) s += __shfl_down(s, o, 64);
    __shared__ float red[16];
    __shared__ float n_sh;
    if ((k & 63) == 0) red[k >> 6] = s;
    __syncthreads();
    if (k == 0) {
        float n = 0.f;
#pragma unroll
        for (int i = 0; i < 16; ++i) n += red[i];
        n_sh = n;
        out[OUT_LOSS] = 0.25f * (ws[WS_LOSS] / 16777216.0f);
    }
    __syncthreads();
    float n = n_sh;
    (ws + WS_SMOOTH)[k] = (nc + 1e-5f) / (n + 0.01024f) * n;
}

__global__ __launch_bounds__(256) void vq_finalize2_kernel(
    const float* __restrict__ ema_es, const float* __restrict__ ws,
    float* __restrict__ out) {
    int i = blockIdx.x * 256 + threadIdx.x;  // 65536 elements
    int k = i >> 6;
    float es = 0.99f * ema_es[i] + 0.01f * (ws + WS_EMBED)[i];
    out[OUT_NEWES + i] = es;
    out[OUT_NEWW + i] = es / (ws + WS_SMOOTH)[k];
}

extern "C" void kernel_launch(void* const* d_in, const int* in_sizes, int n_in,
                              void* d_out, int out_size, void* d_ws, size_t ws_size,
                              hipStream_t stream) {
    const float* z = (const float*)d_in[0];
    const float* weight = (const float*)d_in[1];
    const float* ema_cs = (const float*)d_in[2];
    const float* ema_es = (const float*)d_in[3];
    float* out = (float*)d_out;
    float* ws = (float*)d_ws;

    hipMemsetAsync(ws, 0, (size_t)WS_ZERO_FLOATS * sizeof(float), stream);
    vq_w2_kernel<<<4, 256, 0, stream>>>(weight, ws + WS_W2);
    vq_main_kernel<<<B_ROWS / 256, 256, 0, stream>>>(z, weight, ws, out);
    vq_finalize1_kernel<<<1, 1024, 0, stream>>>(ema_cs, ws, out);
    vq_finalize2_kernel<<<256, 256, 0, stream>>>(ema_es, ws, out);
}

// Round 2
// 1113.948 us; speedup vs baseline: 3.5238x; 3.5238x over previous
//
#include <hip/hip_runtime.h>

#define B_ROWS 262144
#define K_CODES 1024
#define DIM 64

// output layout (floats)
#define OUT_ZQ 0
#define OUT_IDX 16777216
#define OUT_LOSS 17039360
#define OUT_NEWCS 17039361
#define OUT_NEWES 17040385
#define OUT_NEWW 17105921

// ws layout (floats)
#define WS_LOSS 0
#define WS_COUNTS 16
#define WS_W2 2048
#define WS_SMOOTH 3072
#define WS_EMBED 4096

__global__ __launch_bounds__(256) void vq_w2_kernel(const float* __restrict__ w,
                                                    float* __restrict__ w2) {
    int k = blockIdx.x * 256 + threadIdx.x;
    if (k < K_CODES) {
        const float4* w4 = (const float4*)(w + (size_t)k * DIM);
        float s = 0.f;
#pragma unroll
        for (int j = 0; j < 16; ++j) {
            float4 v = w4[j];
            s += v.x * v.x + v.y * v.y + v.z * v.z + v.w * v.w;
        }
        w2[k] = s;
    }
}

__global__ __launch_bounds__(256) void vq_main_kernel(
    const float* __restrict__ z, const float* __restrict__ w,
    float* __restrict__ ws, float* __restrict__ out) {
    __shared__ float lred[4];
    const float* __restrict__ w2 = ws + WS_W2;

    int tid = threadIdx.x;
    int row = blockIdx.x * 256 + tid;

    // load z row into registers (16 x float4)
    const float4* zp = (const float4*)(z + (size_t)row * DIM);
    float zr[DIM];
    float z2 = 0.f;
#pragma unroll
    for (int j = 0; j < 16; ++j) {
        float4 v = zp[j];
        zr[4 * j + 0] = v.x;
        zr[4 * j + 1] = v.y;
        zr[4 * j + 2] = v.z;
        zr[4 * j + 3] = v.w;
    }
#pragma unroll
    for (int d = 0; d < DIM; ++d) z2 = fmaf(zr[d], zr[d], z2);

    // argmin over all codes; d2 = (z2 - 2*dot) + w2[k]; first-min tie-break
    float minv = 3.4e38f;
    int mini = 0;
    for (int k = 0; k < K_CODES; k += 2) {
        const float4* wa = (const float4*)(w + (size_t)k * DIM);
        const float4* wb = (const float4*)(w + (size_t)(k + 1) * DIM);
        float a0 = 0.f, a1 = 0.f;
#pragma unroll
        for (int j = 0; j < 16; ++j) {
            float4 va = wa[j];
            float4 vb = wb[j];
            a0 = fmaf(zr[4 * j + 0], va.x, a0);
            a0 = fmaf(zr[4 * j + 1], va.y, a0);
            a0 = fmaf(zr[4 * j + 2], va.z, a0);
            a0 = fmaf(zr[4 * j + 3], va.w, a0);
            a1 = fmaf(zr[4 * j + 0], vb.x, a1);
            a1 = fmaf(zr[4 * j + 1], vb.y, a1);
            a1 = fmaf(zr[4 * j + 2], vb.z, a1);
            a1 = fmaf(zr[4 * j + 3], vb.w, a1);
        }
        float d0 = (z2 - 2.f * a0) + w2[k];
        float d1 = (z2 - 2.f * a1) + w2[k + 1];
        if (d0 < minv) { minv = d0; mini = k; }
        if (d1 < minv) { minv = d1; mini = k + 1; }
    }

    // gather z_q (old weights), write z_q_st = z + (z_q - z), accumulate loss
    const float4* wq4 = (const float4*)(w + (size_t)mini * DIM);
    float4* outp = (float4*)(out + OUT_ZQ + (size_t)row * DIM);
    float lsum = 0.f;
#pragma unroll
    for (int j = 0; j < 16; ++j) {
        float4 q = wq4[j];
        float x0 = zr[4 * j + 0], x1 = zr[4 * j + 1];
        float x2 = zr[4 * j + 2], x3 = zr[4 * j + 3];
        float4 st;
        st.x = x0 + (q.x - x0);
        st.y = x1 + (q.y - x1);
        st.z = x2 + (q.z - x2);
        st.w = x3 + (q.w - x3);
        outp[j] = st;
        float e0 = x0 - q.x, e1 = x1 - q.y, e2 = x2 - q.z, e3 = x3 - q.w;
        lsum += e0 * e0;
        lsum += e1 * e1;
        lsum += e2 * e2;
        lsum += e3 * e3;
    }
    out[OUT_IDX + row] = (float)mini;

    // loss: wave reduce + block reduce + one global atomic per block
#pragma unroll
    for (int o = 32; o; o >>= 1) lsum += __shfl_down(lsum, o, 64);
    if ((tid & 63) == 0) lred[tid >> 6] = lsum;
    __syncthreads();
    if (tid == 0) atomicAdd(ws + WS_LOSS, lred[0] + lred[1] + lred[2] + lred[3]);
}

// One block per code: scan all indices (L2-resident, coalesced float4),
// ballot for matches, lane=dim gathers matching z rows. No atomics.
__global__ __launch_bounds__(256) void vq_embed_kernel(
    const float* __restrict__ z, const float* __restrict__ idx_f,
    float* __restrict__ ws) {
    int code = blockIdx.x;
    float code_f = (float)code;
    int tid = threadIdx.x;
    int wave = tid >> 6, lane = tid & 63;

    float acc = 0.f;  // lane owns dim = lane
    float cnt = 0.f;

    // each iteration: block covers 1024 rows (4 waves x 64 lanes x 4/f4)
    const float4* idx4 = (const float4*)idx_f;
    for (int i = 0; i < B_ROWS / 1024; ++i) {
        int base = i * 1024 + wave * 256;          // wave covers 256 rows
        float4 f = idx4[(base >> 2) + lane];       // rows base+4*lane .. +3
        unsigned long long m0 = __ballot(f.x == code_f);
        unsigned long long m1 = __ballot(f.y == code_f);
        unsigned long long m2 = __ballot(f.z == code_f);
        unsigned long long m3 = __ballot(f.w == code_f);
        cnt += (f.x == code_f) + (f.y == code_f) + (f.z == code_f) + (f.w == code_f);
        while (m0) { int b = __ffsll(m0) - 1; m0 &= m0 - 1;
            acc += z[(size_t)(base + 4 * b + 0) * DIM + lane]; }
        while (m1) { int b = __ffsll(m1) - 1; m1 &= m1 - 1;
            acc += z[(size_t)(base + 4 * b + 1) * DIM + lane]; }
        while (m2) { int b = __ffsll(m2) - 1; m2 &= m2 - 1;
            acc += z[(size_t)(base + 4 * b + 2) * DIM + lane]; }
        while (m3) { int b = __ffsll(m3) - 1; m3 &= m3 - 1;
            acc += z[(size_t)(base + 4 * b + 3) * DIM + lane]; }
    }

    __shared__ float red[4][DIM];
    __shared__ float cred[4];
    red[wave][lane] = acc;
    // count: reduce within wave
#pragma unroll
    for (int o = 32; o; o >>= 1) cnt += __shfl_down(cnt, o, 64);
    if (lane == 0) cred[wave] = cnt;
    __syncthreads();
    if (wave == 0) {
        float s = red[0][lane] + red[1][lane] + red[2][lane] + red[3][lane];
        ws[WS_EMBED + (size_t)code * DIM + lane] = s;
        if (lane == 0)
            ws[WS_COUNTS + code] = cred[0] + cred[1] + cred[2] + cred[3];
    }
}

__global__ __launch_bounds__(1024) void vq_finalize1_kernel(
    const float* __restrict__ ema_cs, float* __restrict__ ws,
    float* __restrict__ out) {
    int k = threadIdx.x;  // 1024 threads, one per code
    float nc = 0.99f * ema_cs[k] + 0.01f * (ws + WS_COUNTS)[k];
    out[OUT_NEWCS + k] = nc;

    // block-wide sum n = sum(new_cs)
    float s = nc;
#pragma unroll
    for (int o = 32; o; o >>= 1) s += __shfl_down(s, o, 64);
    __shared__ float red[16];
    __shared__ float n_sh;
    if ((k & 63) == 0) red[k >> 6] = s;
    __syncthreads();
    if (k == 0) {
        float n = 0.f;
#pragma unroll
        for (int i = 0; i < 16; ++i) n += red[i];
        n_sh = n;
        out[OUT_LOSS] = 0.25f * (ws[WS_LOSS] / 16777216.0f);
    }
    __syncthreads();
    float n = n_sh;
    (ws + WS_SMOOTH)[k] = (nc + 1e-5f) / (n + 0.01024f) * n;
}

__global__ __launch_bounds__(256) void vq_finalize2_kernel(
    const float* __restrict__ ema_es, const float* __restrict__ ws,
    float* __restrict__ out) {
    int i = blockIdx.x * 256 + threadIdx.x;  // 65536 elements
    int k = i >> 6;
    float es = 0.99f * ema_es[i] + 0.01f * (ws + WS_EMBED)[i];
    out[OUT_NEWES + i] = es;
    out[OUT_NEWW + i] = es / (ws + WS_SMOOTH)[k];
}

extern "C" void kernel_launch(void* const* d_in, const int* in_sizes, int n_in,
                              void* d_out, int out_size, void* d_ws, size_t ws_size,
                              hipStream_t stream) {
    const float* z = (const float*)d_in[0];
    const float* weight = (const float*)d_in[1];
    const float* ema_cs = (const float*)d_in[2];
    const float* ema_es = (const float*)d_in[3];
    float* out = (float*)d_out;
    float* ws = (float*)d_ws;

    hipMemsetAsync(ws, 0, 16 * sizeof(float), stream);  // loss accumulator only
    vq_w2_kernel<<<4, 256, 0, stream>>>(weight, ws + WS_W2);
    vq_main_kernel<<<B_ROWS / 256, 256, 0, stream>>>(z, weight, ws, out);
    vq_embed_kernel<<<K_CODES, 256, 0, stream>>>(z, out + OUT_IDX, ws);
    vq_finalize1_kernel<<<1, 1024, 0, stream>>>(ema_cs, ws, out);
    vq_finalize2_kernel<<<256, 256, 0, stream>>>(ema_es, ws, out);
}

// Round 3
// 829.827 us; speedup vs baseline: 4.7303x; 1.3424x over previous
//
#include <hip/hip_runtime.h>

typedef __attribute__((ext_vector_type(8))) short bf16x8;
typedef __attribute__((ext_vector_type(4))) float f32x4;

#define B_ROWS 262144
#define K_CODES 1024
#define DIM 64
#define DELTA 0.015f

// output layout (floats)
#define OUT_ZQ 0
#define OUT_IDX 16777216
#define OUT_LOSS 17039360
#define OUT_NEWCS 17039361
#define OUT_NEWES 17040385
#define OUT_NEWW 17105921

// ws layout (float indices); total ~5.6 MB
#define WS_LOSS   0
#define WS_QCOUNT 1        // int
#define WS_W2     16       // 1024
#define WS_SMOOTH 1056     // 1024
#define WS_WHI    2080     // ushort[65536] = 32768 floats (16B aligned)
#define WS_WLO    34848    // ushort[65536]
#define WS_CPART  67616    // 4*1024
#define WS_EPART  71712    // 4*65536
#define WS_MINV   333856   // 262144
#define WS_MIN2   596000   // 262144
#define WS_MINI   858144   // int[262144]
#define WS_QUEUE  1120288  // int[262144]

static __device__ __forceinline__ unsigned short f2bf(float x) {
    unsigned u = __float_as_uint(x);
    unsigned r = (u + 0x7fffu + ((u >> 16) & 1u)) >> 16;  // RN-even
    return (unsigned short)r;
}
static __device__ __forceinline__ float bf2f(unsigned short u) {
    return __uint_as_float(((unsigned)u) << 16);
}

__global__ __launch_bounds__(256) void vq_w2_kernel(const float* __restrict__ w,
                                                    float* __restrict__ w2) {
    int k = blockIdx.x * 256 + threadIdx.x;
    if (k < K_CODES) {
        const float4* w4 = (const float4*)(w + (size_t)k * DIM);
        float s = 0.f;
#pragma unroll
        for (int j = 0; j < 16; ++j) {
            float4 v = w4[j];
            s += v.x * v.x + v.y * v.y + v.z * v.z + v.w * v.w;
        }
        w2[k] = s;
    }
}

__global__ __launch_bounds__(256) void vq_wcvt_kernel(const float* __restrict__ w,
                                                      float* __restrict__ ws) {
    int i = blockIdx.x * 256 + threadIdx.x;  // 65536 elems
    unsigned short* whi = (unsigned short*)(ws + WS_WHI);
    unsigned short* wlo = (unsigned short*)(ws + WS_WLO);
    float v = w[i];
    unsigned short h = f2bf(v);
    whi[i] = h;
    wlo[i] = f2bf(v - bf2f(h));
}

// MFMA bf16x2 screening: per wave 16 rows x all 1024 codes.
// dist(k) = w2[k] - 2*dot (z2 omitted: constant per row, cancels in gaps).
__global__ __launch_bounds__(256) void vq_screen_kernel(
    const float* __restrict__ z, float* __restrict__ ws) {
    const unsigned short* __restrict__ whi = (const unsigned short*)(ws + WS_WHI);
    const unsigned short* __restrict__ wlo = (const unsigned short*)(ws + WS_WLO);
    const float* __restrict__ w2 = ws + WS_W2;

    int tid = threadIdx.x;
    int l = tid & 63, q = l >> 4, m = l & 15;
    int rg = blockIdx.x * 4 + (tid >> 6);  // row-group of 16

    // A frags: A[row=l&15][k=q*8+j], row-major z
    const float* zrow = z + ((size_t)rg * 16 + m) * DIM + q * 8;
    float4 f0 = *(const float4*)(zrow);
    float4 f1 = *(const float4*)(zrow + 4);
    float4 f2 = *(const float4*)(zrow + 32);
    float4 f3 = *(const float4*)(zrow + 36);

    bf16x8 ahi0, alo0, ahi1, alo1;
    float tf[16] = {f0.x, f0.y, f0.z, f0.w, f1.x, f1.y, f1.z, f1.w,
                    f2.x, f2.y, f2.z, f2.w, f3.x, f3.y, f3.z, f3.w};
#pragma unroll
    for (int j = 0; j < 8; ++j) {
        unsigned short h0 = f2bf(tf[j]);
        ahi0[j] = (short)h0;
        alo0[j] = (short)f2bf(tf[j] - bf2f(h0));
        unsigned short h1 = f2bf(tf[8 + j]);
        ahi1[j] = (short)h1;
        alo1[j] = (short)f2bf(tf[8 + j] - bf2f(h1));
    }

    float mv[4] = {3.4e38f, 3.4e38f, 3.4e38f, 3.4e38f};
    float m2[4] = {3.4e38f, 3.4e38f, 3.4e38f, 3.4e38f};
    int mi[4] = {0, 0, 0, 0};

#pragma unroll 4
    for (int t = 0; t < 64; ++t) {
        int code0 = t * 16 + m;
        const unsigned short* bh = whi + code0 * DIM + q * 8;
        const unsigned short* bl = wlo + code0 * DIM + q * 8;
        bf16x8 bhi0 = *(const bf16x8*)bh;
        bf16x8 bhi1 = *(const bf16x8*)(bh + 32);
        bf16x8 blo0 = *(const bf16x8*)bl;
        bf16x8 blo1 = *(const bf16x8*)(bl + 32);
        f32x4 acc = {0.f, 0.f, 0.f, 0.f};
        acc = __builtin_amdgcn_mfma_f32_16x16x32_bf16(alo0, bhi0, acc, 0, 0, 0);
        acc = __builtin_amdgcn_mfma_f32_16x16x32_bf16(ahi0, blo0, acc, 0, 0, 0);
        acc = __builtin_amdgcn_mfma_f32_16x16x32_bf16(alo1, bhi1, acc, 0, 0, 0);
        acc = __builtin_amdgcn_mfma_f32_16x16x32_bf16(ahi1, blo1, acc, 0, 0, 0);
        acc = __builtin_amdgcn_mfma_f32_16x16x32_bf16(ahi0, bhi0, acc, 0, 0, 0);
        acc = __builtin_amdgcn_mfma_f32_16x16x32_bf16(ahi1, bhi1, acc, 0, 0, 0);
        float w2v = w2[code0];
#pragma unroll
        for (int r = 0; r < 4; ++r) {
            float d = fmaf(acc[r], -2.0f, w2v);
            bool lt = d < mv[r];
            float t2 = fminf(d, m2[r]);
            m2[r] = lt ? mv[r] : t2;
            mv[r] = lt ? d : mv[r];
            mi[r] = lt ? code0 : mi[r];
        }
    }

    // reduce across the 16 lanes sharing q (they hold different codes, same rows)
#pragma unroll
    for (int o = 1; o < 16; o <<= 1) {
#pragma unroll
        for (int r = 0; r < 4; ++r) {
            float ov = __shfl_xor(mv[r], o, 64);
            float ov2 = __shfl_xor(m2[r], o, 64);
            int oi = __shfl_xor(mi[r], o, 64);
            float nm2 = fminf(fminf(m2[r], ov2), fmaxf(mv[r], ov));
            bool take = (ov < mv[r]) || (ov == mv[r] && oi < mi[r]);
            mv[r] = take ? ov : mv[r];
            mi[r] = take ? oi : mi[r];
            m2[r] = nm2;
        }
    }
    if (m == 0) {
#pragma unroll
        for (int r = 0; r < 4; ++r) {
            int row = rg * 16 + q * 4 + r;  // C/D: row=(lane>>4)*4+reg
            ws[WS_MINV + row] = mv[r];
            ws[WS_MIN2 + row] = m2[r];
            ((int*)ws)[WS_MINI + row] = mi[r];
        }
    }
}

// Per-row: unambiguous -> write idx, z_q_st, loss; ambiguous -> enqueue.
__global__ __launch_bounds__(256) void vq_gather_kernel(
    const float* __restrict__ z, const float* __restrict__ w,
    float* __restrict__ ws, float* __restrict__ out) {
    __shared__ float lred[4];
    int tid = threadIdx.x;
    int row = blockIdx.x * 256 + tid;
    float mv = ws[WS_MINV + row];
    float m2 = ws[WS_MIN2 + row];
    int mi = ((const int*)ws)[WS_MINI + row];
    float lsum = 0.f;
    if (m2 - mv > DELTA) {
        out[OUT_IDX + row] = (float)mi;
        const float4* zp = (const float4*)(z + (size_t)row * DIM);
        const float4* wq4 = (const float4*)(w + (size_t)mi * DIM);
        float4* outp = (float4*)(out + OUT_ZQ + (size_t)row * DIM);
#pragma unroll
        for (int j = 0; j < 16; ++j) {
            float4 x = zp[j];
            float4 qv = wq4[j];
            float4 st;
            st.x = x.x + (qv.x - x.x);
            st.y = x.y + (qv.y - x.y);
            st.z = x.z + (qv.z - x.z);
            st.w = x.w + (qv.w - x.w);
            outp[j] = st;
            float e0 = x.x - qv.x, e1 = x.y - qv.y, e2 = x.z - qv.z, e3 = x.w - qv.w;
            lsum += e0 * e0;
            lsum += e1 * e1;
            lsum += e2 * e2;
            lsum += e3 * e3;
        }
    } else {
        int pos = atomicAdd((int*)ws + WS_QCOUNT, 1);
        ((int*)ws)[WS_QUEUE + pos] = row;
    }
#pragma unroll
    for (int o = 32; o; o >>= 1) lsum += __shfl_down(lsum, o, 64);
    if ((tid & 63) == 0) lred[tid >> 6] = lsum;
    __syncthreads();
    if (tid == 0) atomicAdd(ws + WS_LOSS, lred[0] + lred[1] + lred[2] + lred[3]);
}

// One wave per ambiguous row: exact fp32 argmin identical to R2's arithmetic.
__global__ __launch_bounds__(256) void vq_fixup_kernel(
    const float* __restrict__ z, const float* __restrict__ w,
    float* __restrict__ ws, float* __restrict__ out) {
    const float* __restrict__ w2 = ws + WS_W2;
    int count = ((const int*)ws)[WS_QCOUNT];
    int lane = threadIdx.x & 63;
    int wv = (blockIdx.x * 256 + threadIdx.x) >> 6;
    int nw = (gridDim.x * 256) >> 6;
    for (int qi = wv; qi < count; qi += nw) {
        int row = ((const int*)ws)[WS_QUEUE + qi];
        const float* zr = z + (size_t)row * DIM;
        float zloc[DIM];
#pragma unroll
        for (int d = 0; d < DIM; ++d) zloc[d] = zr[d];
        float z2 = 0.f;
#pragma unroll
        for (int d = 0; d < DIM; ++d) z2 = fmaf(zloc[d], zloc[d], z2);
        float best = 3.4e38f;
        int bi = 0;
        for (int i = 0; i < 16; ++i) {
            int c = i * 64 + lane;
            const float* wr = w + (size_t)c * DIM;
            float a = 0.f;
#pragma unroll
            for (int d = 0; d < DIM; ++d) a = fmaf(zloc[d], wr[d], a);
            float dd = (z2 - 2.f * a) + w2[c];
            if (dd < best) { best = dd; bi = c; }
        }
#pragma unroll
        for (int o = 1; o < 64; o <<= 1) {
            float ov = __shfl_xor(best, o, 64);
            int oi = __shfl_xor(bi, o, 64);
            if (ov < best || (ov == best && oi < bi)) { best = ov; bi = oi; }
        }
        float x = zr[lane];
        float qv = w[(size_t)bi * DIM + lane];
        out[OUT_ZQ + (size_t)row * DIM + lane] = x + (qv - x);
        float e = x - qv;
        float s = e * e;
#pragma unroll
        for (int o = 32; o; o >>= 1) s += __shfl_down(s, o, 64);
        if (lane == 0) {
            out[OUT_IDX + row] = (float)bi;
            atomicAdd(ws + WS_LOSS, s);
        }
    }
}

// Segment-sum: 4 splits per code (4096 blocks), partials in ws, no atomics.
__global__ __launch_bounds__(256) void vq_embed_kernel(
    const float* __restrict__ z, const float* __restrict__ idx_f,
    float* __restrict__ ws) {
    int code = blockIdx.x & (K_CODES - 1);
    int split = blockIdx.x >> 10;
    float code_f = (float)code;
    int tid = threadIdx.x;
    int wave = tid >> 6, lane = tid & 63;

    float acc = 0.f;  // lane owns dim = lane
    float cnt = 0.f;

    const float4* idx4 = (const float4*)idx_f;
    int base0 = split * (B_ROWS / 4);
    for (int i = 0; i < B_ROWS / 4096; ++i) {
        int base = base0 + i * 1024 + wave * 256;
        float4 f = idx4[(base >> 2) + lane];
        unsigned long long m0 = __ballot(f.x == code_f);
        unsigned long long m1 = __ballot(f.y == code_f);
        unsigned long long m2 = __ballot(f.z == code_f);
        unsigned long long m3 = __ballot(f.w == code_f);
        cnt += (f.x == code_f) + (f.y == code_f) + (f.z == code_f) + (f.w == code_f);
        while (m0) { int b = __ffsll(m0) - 1; m0 &= m0 - 1;
            acc += z[(size_t)(base + 4 * b + 0) * DIM + lane]; }
        while (m1) { int b = __ffsll(m1) - 1; m1 &= m1 - 1;
            acc += z[(size_t)(base + 4 * b + 1) * DIM + lane]; }
        while (m2) { int b = __ffsll(m2) - 1; m2 &= m2 - 1;
            acc += z[(size_t)(base + 4 * b + 2) * DIM + lane]; }
        while (m3) { int b = __ffsll(m3) - 1; m3 &= m3 - 1;
            acc += z[(size_t)(base + 4 * b + 3) * DIM + lane]; }
    }

    __shared__ float red[4][DIM];
    __shared__ float cred[4];
    red[wave][lane] = acc;
#pragma unroll
    for (int o = 32; o; o >>= 1) cnt += __shfl_down(cnt, o, 64);
    if (lane == 0) cred[wave] = cnt;
    __syncthreads();
    if (wave == 0) {
        float s = red[0][lane] + red[1][lane] + red[2][lane] + red[3][lane];
        ws[WS_EPART + split * (K_CODES * DIM) + (size_t)code * DIM + lane] = s;
        if (lane == 0)
            ws[WS_CPART + split * K_CODES + code] = cred[0] + cred[1] + cred[2] + cred[3];
    }
}

__global__ __launch_bounds__(1024) void vq_finalize1_kernel(
    const float* __restrict__ ema_cs, float* __restrict__ ws,
    float* __restrict__ out) {
    int k = threadIdx.x;
    float c = ws[WS_CPART + k] + ws[WS_CPART + K_CODES + k] +
              ws[WS_CPART + 2 * K_CODES + k] + ws[WS_CPART + 3 * K_CODES + k];
    float nc = 0.99f * ema_cs[k] + 0.01f * c;
    out[OUT_NEWCS + k] = nc;

    float s = nc;
#pragma unroll
    for (int o = 32; o; o >>= 1) s += __shfl_down(s, o, 64);
    __shared__ float red[16];
    __shared__ float n_sh;
    if ((k & 63) == 0) red[k >> 6] = s;
    __syncthreads();
    if (k == 0) {
        float n = 0.f;
#pragma unroll
        for (int i = 0; i < 16; ++i) n += red[i];
        n_sh = n;
        out[OUT_LOSS] = 0.25f * (ws[WS_LOSS] / 16777216.0f);
    }
    __syncthreads();
    float n = n_sh;
    ws[WS_SMOOTH + k] = (nc + 1e-5f) / (n + 0.01024f) * n;
}

__global__ __launch_bounds__(256) void vq_finalize2_kernel(
    const float* __restrict__ ema_es, const float* __restrict__ ws,
    float* __restrict__ out) {
    int i = blockIdx.x * 256 + threadIdx.x;  // 65536 elems
    int k = i >> 6;
    float e = ws[WS_EPART + i] + ws[WS_EPART + 65536 + i] +
              ws[WS_EPART + 2 * 65536 + i] + ws[WS_EPART + 3 * 65536 + i];
    float es = 0.99f * ema_es[i] + 0.01f * e;
    out[OUT_NEWES + i] = es;
    out[OUT_NEWW + i] = es / ws[WS_SMOOTH + k];
}

extern "C" void kernel_launch(void* const* d_in, const int* in_sizes, int n_in,
                              void* d_out, int out_size, void* d_ws, size_t ws_size,
                              hipStream_t stream) {
    const float* z = (const float*)d_in[0];
    const float* weight = (const float*)d_in[1];
    const float* ema_cs = (const float*)d_in[2];
    const float* ema_es = (const float*)d_in[3];
    float* out = (float*)d_out;
    float* ws = (float*)d_ws;

    hipMemsetAsync(ws, 0, 64, stream);  // loss + queue counter
    vq_w2_kernel<<<4, 256, 0, stream>>>(weight, ws + WS_W2);
    vq_wcvt_kernel<<<256, 256, 0, stream>>>(weight, ws);
    vq_screen_kernel<<<B_ROWS / 64, 256, 0, stream>>>(z, ws);
    vq_gather_kernel<<<B_ROWS / 256, 256, 0, stream>>>(z, weight, ws, out);
    vq_fixup_kernel<<<128, 256, 0, stream>>>(z, weight, ws, out);
    vq_embed_kernel<<<4 * K_CODES, 256, 0, stream>>>(z, out + OUT_IDX, ws);
    vq_finalize1_kernel<<<1, 1024, 0, stream>>>(ema_cs, ws, out);
    vq_finalize2_kernel<<<256, 256, 0, stream>>>(ema_es, ws, out);
}

// Round 4
// 448.613 us; speedup vs baseline: 8.7499x; 1.8498x over previous
//
#include <hip/hip_runtime.h>

typedef __attribute__((ext_vector_type(8))) short bf16x8;
typedef __attribute__((ext_vector_type(4))) float f32x4;

#define B_ROWS 262144
#define K_CODES 1024
#define DIM 64
#define DELTA 0.015f
#define ESPLIT 8

// output layout (floats)
#define OUT_ZQ 0
#define OUT_IDX 16777216
#define OUT_LOSS 17039360
#define OUT_NEWCS 17039361
#define OUT_NEWES 17040385
#define OUT_NEWW 17105921

// ws layout (float indices); total ~4.5 MB
#define WS_LOSS   0
#define WS_QCOUNT 1        // int
#define WS_W2     16       // 1024
#define WS_SMOOTH 1056     // 1024
#define WS_WHI    2080     // ushort[65536] (16B aligned: 2080*4=8320)
#define WS_WLO    34848    // ushort[65536]
#define WS_CPART  67616    // 8*1024
#define WS_EPART  75808    // 8*65536
#define WS_MINI   600096   // int[262144]; sign bit = ambiguous
#define WS_QUEUE  862240   // int[262144]

static __device__ __forceinline__ unsigned short f2bf(float x) {
    unsigned u = __float_as_uint(x);
    unsigned r = (u + 0x7fffu + ((u >> 16) & 1u)) >> 16;  // RN-even
    return (unsigned short)r;
}
static __device__ __forceinline__ float bf2f(unsigned short u) {
    return __uint_as_float(((unsigned)u) << 16);
}

__global__ __launch_bounds__(256) void vq_w2_kernel(const float* __restrict__ w,
                                                    float* __restrict__ w2) {
    int k = blockIdx.x * 256 + threadIdx.x;
    if (k < K_CODES) {
        const float4* w4 = (const float4*)(w + (size_t)k * DIM);
        float s = 0.f;
#pragma unroll
        for (int j = 0; j < 16; ++j) {
            float4 v = w4[j];
            s += v.x * v.x + v.y * v.y + v.z * v.z + v.w * v.w;
        }
        w2[k] = s;
    }
}

__global__ __launch_bounds__(256) void vq_wcvt_kernel(const float* __restrict__ w,
                                                      float* __restrict__ ws) {
    int i = blockIdx.x * 256 + threadIdx.x;  // 16384 threads x 4 elems
    ushort4* whi = (ushort4*)(ws + WS_WHI);
    ushort4* wlo = (ushort4*)(ws + WS_WLO);
    float4 v = ((const float4*)w)[i];
    ushort4 h, l;
    h.x = f2bf(v.x); l.x = f2bf(v.x - bf2f(h.x));
    h.y = f2bf(v.y); l.y = f2bf(v.y - bf2f(h.y));
    h.z = f2bf(v.z); l.z = f2bf(v.z - bf2f(h.z));
    h.w = f2bf(v.w); l.w = f2bf(v.w - bf2f(h.w));
    whi[i] = h;
    wlo[i] = l;
}

static __device__ __forceinline__ void cvt_frag(const float* zrow, bf16x8& hi, bf16x8& lo) {
    float4 f0 = *(const float4*)zrow;
    float4 f1 = *(const float4*)(zrow + 4);
    float tf[8] = {f0.x, f0.y, f0.z, f0.w, f1.x, f1.y, f1.z, f1.w};
#pragma unroll
    for (int j = 0; j < 8; ++j) {
        unsigned short h = f2bf(tf[j]);
        hi[j] = (short)h;
        lo[j] = (short)f2bf(tf[j] - bf2f(h));
    }
}

// MFMA screening: block = 4 waves x 32 rows = 128 rows, all 1024 codes.
// Codebook hi/lo staged to LDS in 128-code chunks (row stride 72 ushorts:
// 2-way bank pattern = free). dist = w2[k] - 2*dot (z2 constant per row).
__global__ __launch_bounds__(256) void vq_screen_kernel(
    const float* __restrict__ z, float* __restrict__ ws) {
    __shared__ __align__(16) unsigned short lds_h[128 * 72];
    __shared__ __align__(16) unsigned short lds_l[128 * 72];
    __shared__ float lds_w2[K_CODES];

    int tid = threadIdx.x;
    int l = tid & 63, q = l >> 4, m = l & 15;
    int wave = tid >> 6;

    // w2 -> LDS (once)
    *(float4*)&lds_w2[tid * 4] = ((const float4*)(ws + WS_W2))[tid];

    // A fragments for 2 row-groups of 16: A[row=m][k=q*8+j]
    int row0 = blockIdx.x * 128 + wave * 32 + m;
    bf16x8 ahi[2][2], alo[2][2];
#pragma unroll
    for (int g = 0; g < 2; ++g) {
        const float* zr = z + (size_t)(row0 + g * 16) * DIM + q * 8;
        cvt_frag(zr, ahi[g][0], alo[g][0]);
        cvt_frag(zr + 32, ahi[g][1], alo[g][1]);
    }

    float mv[8], m2[8];
    int mi[8];
#pragma unroll
    for (int v = 0; v < 8; ++v) { mv[v] = 3.4e38f; m2[v] = 3.4e38f; mi[v] = 0; }

    const uint4* gh = (const uint4*)(ws + WS_WHI);
    const uint4* gl = (const uint4*)(ws + WS_WLO);

    for (int cch = 0; cch < 8; ++cch) {
        if (cch) __syncthreads();
        // stage 128-code chunk: 1024 x 16B per array, padded rows
#pragma unroll
        for (int j = 0; j < 4; ++j) {
            int chunk = tid + j * 256;           // 0..1023
            int r = chunk >> 3, c8 = chunk & 7;  // row, 16B-col
            *(uint4*)&lds_h[r * 72 + c8 * 8] = gh[cch * 1024 + chunk];
            *(uint4*)&lds_l[r * 72 + c8 * 8] = gl[cch * 1024 + chunk];
        }
        __syncthreads();

#pragma unroll 2
        for (int tg = 0; tg < 8; ++tg) {
            int cl = tg * 16 + m;  // local code row
            bf16x8 bhi0 = *(const bf16x8*)&lds_h[cl * 72 + q * 8];
            bf16x8 bhi1 = *(const bf16x8*)&lds_h[cl * 72 + 32 + q * 8];
            bf16x8 blo0 = *(const bf16x8*)&lds_l[cl * 72 + q * 8];
            bf16x8 blo1 = *(const bf16x8*)&lds_l[cl * 72 + 32 + q * 8];
            float w2v = lds_w2[cch * 128 + tg * 16 + m];
            int cg = cch * 128 + tg * 16 + m;
#pragma unroll
            for (int g = 0; g < 2; ++g) {
                f32x4 acc = {0.f, 0.f, 0.f, 0.f};
                acc = __builtin_amdgcn_mfma_f32_16x16x32_bf16(alo[g][0], bhi0, acc, 0, 0, 0);
                acc = __builtin_amdgcn_mfma_f32_16x16x32_bf16(ahi[g][0], blo0, acc, 0, 0, 0);
                acc = __builtin_amdgcn_mfma_f32_16x16x32_bf16(alo[g][1], bhi1, acc, 0, 0, 0);
                acc = __builtin_amdgcn_mfma_f32_16x16x32_bf16(ahi[g][1], blo1, acc, 0, 0, 0);
                acc = __builtin_amdgcn_mfma_f32_16x16x32_bf16(ahi[g][0], bhi0, acc, 0, 0, 0);
                acc = __builtin_amdgcn_mfma_f32_16x16x32_bf16(ahi[g][1], bhi1, acc, 0, 0, 0);
#pragma unroll
                for (int r = 0; r < 4; ++r) {
                    int v = g * 4 + r;
                    float d = fmaf(acc[r], -2.0f, w2v);
                    bool lt = d < mv[v];
                    m2[v] = lt ? mv[v] : fminf(d, m2[v]);
                    mv[v] = lt ? d : mv[v];
                    mi[v] = lt ? cg : mi[v];
                }
            }
        }
    }

    // reduce across the 16 lanes sharing q (different codes, same rows)
#pragma unroll
    for (int o = 1; o < 16; o <<= 1) {
#pragma unroll
        for (int v = 0; v < 8; ++v) {
            float ov = __shfl_xor(mv[v], o, 64);
            float ov2 = __shfl_xor(m2[v], o, 64);
            int oi = __shfl_xor(mi[v], o, 64);
            float nm2 = fminf(fminf(m2[v], ov2), fmaxf(mv[v], ov));
            bool take = (ov < mv[v]) || (ov == mv[v] && oi < mi[v]);
            mv[v] = take ? ov : mv[v];
            mi[v] = take ? oi : mi[v];
            m2[v] = nm2;
        }
    }
    if (m == 0) {
#pragma unroll
        for (int v = 0; v < 8; ++v) {
            int g = v >> 2, r = v & 3;
            int row = blockIdx.x * 128 + wave * 32 + g * 16 + q * 4 + r;
            bool amb = (m2[v] - mv[v] <= DELTA);
            ((int*)ws)[WS_MINI + row] = mi[v] | (amb ? 0x80000000 : 0);
        }
    }
}

// Per-row: unambiguous -> write idx, z_q_st, loss; ambiguous -> enqueue.
__global__ __launch_bounds__(256) void vq_gather_kernel(
    const float* __restrict__ z, const float* __restrict__ w,
    float* __restrict__ ws, float* __restrict__ out) {
    __shared__ float lred[4];
    int tid = threadIdx.x;
    int row = blockIdx.x * 256 + tid;
    int enc = ((const int*)ws)[WS_MINI + row];
    float lsum = 0.f;
    if (enc >= 0) {
        int mi = enc;
        out[OUT_IDX + row] = (float)mi;
        const float4* zp = (const float4*)(z + (size_t)row * DIM);
        const float4* wq4 = (const float4*)(w + (size_t)mi * DIM);
        float4* outp = (float4*)(out + OUT_ZQ + (size_t)row * DIM);
#pragma unroll
        for (int j = 0; j < 16; ++j) {
            float4 x = zp[j];
            float4 qv = wq4[j];
            float4 st;
            st.x = x.x + (qv.x - x.x);
            st.y = x.y + (qv.y - x.y);
            st.z = x.z + (qv.z - x.z);
            st.w = x.w + (qv.w - x.w);
            outp[j] = st;
            float e0 = x.x - qv.x, e1 = x.y - qv.y, e2 = x.z - qv.z, e3 = x.w - qv.w;
            lsum += e0 * e0;
            lsum += e1 * e1;
            lsum += e2 * e2;
            lsum += e3 * e3;
        }
    } else {
        int pos = atomicAdd((int*)ws + WS_QCOUNT, 1);
        ((int*)ws)[WS_QUEUE + pos] = row;
    }
#pragma unroll
    for (int o = 32; o; o >>= 1) lsum += __shfl_down(lsum, o, 64);
    if ((tid & 63) == 0) lred[tid >> 6] = lsum;
    __syncthreads();
    if (tid == 0) atomicAdd(ws + WS_LOSS, lred[0] + lred[1] + lred[2] + lred[3]);
}

// One wave per ambiguous row: exact fp32 argmin (same arithmetic as ref path).
__global__ __launch_bounds__(256) void vq_fixup_kernel(
    const float* __restrict__ z, const float* __restrict__ w,
    float* __restrict__ ws, float* __restrict__ out) {
    const float* __restrict__ w2 = ws + WS_W2;
    int count = ((const int*)ws)[WS_QCOUNT];
    int lane = threadIdx.x & 63;
    int wv = (blockIdx.x * 256 + threadIdx.x) >> 6;
    int nw = (gridDim.x * 256) >> 6;
    for (int qi = wv; qi < count; qi += nw) {
        int row = ((const int*)ws)[WS_QUEUE + qi];
        const float* zr = z + (size_t)row * DIM;
        float zloc[DIM];
#pragma unroll
        for (int d = 0; d < DIM; ++d) zloc[d] = zr[d];
        float z2 = 0.f;
#pragma unroll
        for (int d = 0; d < DIM; ++d) z2 = fmaf(zloc[d], zloc[d], z2);
        float best = 3.4e38f;
        int bi = 0;
        for (int i = 0; i < 16; ++i) {
            int c = i * 64 + lane;
            const float* wr = w + (size_t)c * DIM;
            float a = 0.f;
#pragma unroll
            for (int d = 0; d < DIM; ++d) a = fmaf(zloc[d], wr[d], a);
            float dd = (z2 - 2.f * a) + w2[c];
            if (dd < best) { best = dd; bi = c; }
        }
#pragma unroll
        for (int o = 1; o < 64; o <<= 1) {
            float ov = __shfl_xor(best, o, 64);
            int oi = __shfl_xor(bi, o, 64);
            if (ov < best || (ov == best && oi < bi)) { best = ov; bi = oi; }
        }
        float x = zr[lane];
        float qv = w[(size_t)bi * DIM + lane];
        out[OUT_ZQ + (size_t)row * DIM + lane] = x + (qv - x);
        float e = x - qv;
        float s = e * e;
#pragma unroll
        for (int o = 32; o; o >>= 1) s += __shfl_down(s, o, 64);
        if (lane == 0) {
            out[OUT_IDX + row] = (float)bi;
            atomicAdd(ws + WS_LOSS, s);
        }
    }
}

// Segment-sum: ESPLIT splits per code, partials in ws, no atomics.
__global__ __launch_bounds__(256) void vq_embed_kernel(
    const float* __restrict__ z, const float* __restrict__ idx_f,
    float* __restrict__ ws) {
    int code = blockIdx.x & (K_CODES - 1);
    int split = blockIdx.x >> 10;
    float code_f = (float)code;
    int tid = threadIdx.x;
    int wave = tid >> 6, lane = tid & 63;

    float acc = 0.f;  // lane owns dim = lane
    float cnt = 0.f;

    const float4* idx4 = (const float4*)idx_f;
    int base0 = split * (B_ROWS / ESPLIT);
    for (int i = 0; i < B_ROWS / (ESPLIT * 1024); ++i) {
        int base = base0 + i * 1024 + wave * 256;
        float4 f = idx4[(base >> 2) + lane];
        unsigned long long m0 = __ballot(f.x == code_f);
        unsigned long long m1 = __ballot(f.y == code_f);
        unsigned long long m2 = __ballot(f.z == code_f);
        unsigned long long m3 = __ballot(f.w == code_f);
        cnt += (f.x == code_f) + (f.y == code_f) + (f.z == code_f) + (f.w == code_f);
        while (m0) { int b = __ffsll(m0) - 1; m0 &= m0 - 1;
            acc += z[(size_t)(base + 4 * b + 0) * DIM + lane]; }
        while (m1) { int b = __ffsll(m1) - 1; m1 &= m1 - 1;
            acc += z[(size_t)(base + 4 * b + 1) * DIM + lane]; }
        while (m2) { int b = __ffsll(m2) - 1; m2 &= m2 - 1;
            acc += z[(size_t)(base + 4 * b + 2) * DIM + lane]; }
        while (m3) { int b = __ffsll(m3) - 1; m3 &= m3 - 1;
            acc += z[(size_t)(base + 4 * b + 3) * DIM + lane]; }
    }

    __shared__ float red[4][DIM];
    __shared__ float cred[4];
    red[wave][lane] = acc;
#pragma unroll
    for (int o = 32; o; o >>= 1) cnt += __shfl_down(cnt, o, 64);
    if (lane == 0) cred[wave] = cnt;
    __syncthreads();
    if (wave == 0) {
        float s = red[0][lane] + red[1][lane] + red[2][lane] + red[3][lane];
        ws[WS_EPART + split * (K_CODES * DIM) + (size_t)code * DIM + lane] = s;
        if (lane == 0)
            ws[WS_CPART + split * K_CODES + code] = cred[0] + cred[1] + cred[2] + cred[3];
    }
}

__global__ __launch_bounds__(1024) void vq_finalize1_kernel(
    const float* __restrict__ ema_cs, float* __restrict__ ws,
    float* __restrict__ out) {
    int k = threadIdx.x;
    float c = 0.f;
#pragma unroll
    for (int j = 0; j < ESPLIT; ++j) c += ws[WS_CPART + j * K_CODES + k];
    float nc = 0.99f * ema_cs[k] + 0.01f * c;
    out[OUT_NEWCS + k] = nc;

    float s = nc;
#pragma unroll
    for (int o = 32; o; o >>= 1) s += __shfl_down(s, o, 64);
    __shared__ float red[16];
    __shared__ float n_sh;
    if ((k & 63) == 0) red[k >> 6] = s;
    __syncthreads();
    if (k == 0) {
        float n = 0.f;
#pragma unroll
        for (int i = 0; i < 16; ++i) n += red[i];
        n_sh = n;
        out[OUT_LOSS] = 0.25f * (ws[WS_LOSS] / 16777216.0f);
    }
    __syncthreads();
    float n = n_sh;
    ws[WS_SMOOTH + k] = (nc + 1e-5f) / (n + 0.01024f) * n;
}

__global__ __launch_bounds__(256) void vq_finalize2_kernel(
    const float* __restrict__ ema_es, const float* __restrict__ ws,
    float* __restrict__ out) {
    int i = blockIdx.x * 256 + threadIdx.x;  // 65536 elems
    int k = i >> 6;
    float e = 0.f;
#pragma unroll
    for (int j = 0; j < ESPLIT; ++j) e += ws[WS_EPART + j * 65536 + i];
    float es = 0.99f * ema_es[i] + 0.01f * e;
    out[OUT_NEWES + i] = es;
    out[OUT_NEWW + i] = es / ws[WS_SMOOTH + k];
}

extern "C" void kernel_launch(void* const* d_in, const int* in_sizes, int n_in,
                              void* d_out, int out_size, void* d_ws, size_t ws_size,
                              hipStream_t stream) {
    const float* z = (const float*)d_in[0];
    const float* weight = (const float*)d_in[1];
    const float* ema_cs = (const float*)d_in[2];
    const float* ema_es = (const float*)d_in[3];
    float* out = (float*)d_out;
    float* ws = (float*)d_ws;

    hipMemsetAsync(ws, 0, 64, stream);  // loss + queue counter
    vq_w2_kernel<<<4, 256, 0, stream>>>(weight, ws + WS_W2);
    vq_wcvt_kernel<<<64, 256, 0, stream>>>(weight, ws);
    vq_screen_kernel<<<B_ROWS / 128, 256, 0, stream>>>(z, ws);
    vq_gather_kernel<<<B_ROWS / 256, 256, 0, stream>>>(z, weight, ws, out);
    vq_fixup_kernel<<<128, 256, 0, stream>>>(z, weight, ws, out);
    vq_embed_kernel<<<ESPLIT * K_CODES, 256, 0, stream>>>(z, out + OUT_IDX, ws);
    vq_finalize1_kernel<<<1, 1024, 0, stream>>>(ema_cs, ws, out);
    vq_finalize2_kernel<<<256, 256, 0, stream>>>(ema_es, ws, out);
}